// Round 1
// baseline (311.364 us; speedup 1.0000x reference)
//
#include <hip/hip_runtime.h>

#define NQ 2048
#define NK 512
#define DD 128

typedef __bf16 bf16_t;
typedef bf16_t bf16x4 __attribute__((ext_vector_type(4)));
typedef bf16_t bf16x8 __attribute__((ext_vector_type(8)));
typedef float  f32x4  __attribute__((ext_vector_type(4)));

// swizzled index into row-major [row][128] bf16 LDS tile (XOR byte-swizzle, G4/T2)
__device__ __forceinline__ int swz(int row, int d) {
  return row * 128 + (d ^ ((row & 7) << 3));
}

__device__ __forceinline__ float blockSum(float v, volatile float* sRed) {
  #pragma unroll
  for (int m = 32; m; m >>= 1) v += __shfl_xor(v, m);
  __syncthreads();                       // protect sRed from previous use
  if ((threadIdx.x & 63) == 0) sRed[threadIdx.x >> 6] = v;
  __syncthreads();
  return sRed[0] + sRed[1] + sRed[2] + sRed[3];
}

__device__ __forceinline__ float blockMax(float v, volatile float* sRed) {
  #pragma unroll
  for (int m = 32; m; m >>= 1) v = fmaxf(v, __shfl_xor(v, m));
  __syncthreads();
  if ((threadIdx.x & 63) == 0) sRed[threadIdx.x >> 6] = v;
  __syncthreads();
  return fmaxf(fmaxf(sRed[0], sRed[1]), fmaxf(sRed[2], sRed[3]));
}

__global__ __launch_bounds__(256) void fused_np_attn(
    const float* __restrict__ Q,   const float* __restrict__ K,
    const float* __restrict__ V,   const float* __restrict__ eps,
    const float* __restrict__ Wmu, const float* __restrict__ bmu,
    const float* __restrict__ Wlv, const float* __restrict__ blv,
    const float* __restrict__ Wp1, const float* __restrict__ bp1,
    const float* __restrict__ Wp2, const float* __restrict__ bp2,
    const float* __restrict__ gamma, const float* __restrict__ beta,
    float* __restrict__ out, float* __restrict__ klp)
{
  __shared__ __align__(16) bf16_t sW[128 * 128];  // W_pr1 [e][d] bf16, swizzled (32 KB)
  __shared__ __align__(16) bf16_t sK[64 * 128];   // K chunk [key][d] bf16, swizzled (16 KB); aliased as sCtx
  __shared__ float sB1[128], sW2[128], sWm2[128], sWl2[128];
  __shared__ float sKmu[NK], sKlv[NK], sMup[NK], sS[NK];
  __shared__ float sRed[4];

  const int q    = blockIdx.x;
  const int t    = threadIdx.x;
  const int lane = t & 63;
  const int wave = t >> 6;

  // ---- stage small vectors
  if (t < 128) {
    sB1[t]  = bp1[t];
    sW2[t]  = Wp2[t];
    sWm2[t] = Wmu[128 + t];
    sWl2[t] = Wlv[128 + t];
  }
  // ---- stage W_pr1 -> bf16 swizzled. thread t: row = t>>1, 64 cols
  {
    int row = t >> 1, d0 = (t & 1) * 64;
    const float* src = Wp1 + row * 128 + d0;
    #pragma unroll
    for (int i = 0; i < 8; ++i) {
      float4 f0 = *(const float4*)(src + i * 8);
      float4 f1 = *(const float4*)(src + i * 8 + 4);
      bf16x8 v = {(bf16_t)f0.x, (bf16_t)f0.y, (bf16_t)f0.z, (bf16_t)f0.w,
                  (bf16_t)f1.x, (bf16_t)f1.y, (bf16_t)f1.z, (bf16_t)f1.w};
      *(bf16x8*)(&sW[swz(row, d0 + i * 8)]) = v;
    }
  }
  // ---- qmu, qlv = Q[q] . Wmu[:128], Wlv[:128]
  float pm = 0.f, pl = 0.f;
  if (t < 128) {
    float qv = Q[(size_t)q * 128 + t];
    pm = qv * Wmu[t];
    pl = qv * Wlv[t];
  }
  __syncthreads();   // sW / small vectors ready; then reduce
  const float qmu = blockSum(pm, sRed);
  const float qlv = blockSum(pl, sRed);

  const float b_mu = bmu[0], b_lv = blv[0], b_p2 = bp2[0];

  // ================= chunked K processing =================
  const int rg = lane >> 4;    // 0..3 : k-group
  const int rr = lane & 15;    // 0..15: row-in-tile (A) / col e (B/D)

  for (int chunk = 0; chunk < 8; ++chunk) {
    // ---- stage 64 keys x 128 d: thread t -> key=t>>2, d-range 32*(t&3)
    {
      int key  = t >> 2;
      int gkey = chunk * 64 + key;
      int d0   = (t & 3) * 32;
      const float* src = K + (((size_t)q * NK + gkey) * 128 + d0);
      float4 f[8];
      #pragma unroll
      for (int i = 0; i < 8; ++i) f[i] = *(const float4*)(src + i * 4);
      float kmu_p = 0.f, klv_p = 0.f;
      #pragma unroll
      for (int i = 0; i < 8; ++i) {
        int b = d0 + i * 4;
        kmu_p += f[i].x * sWm2[b] + f[i].y * sWm2[b + 1] + f[i].z * sWm2[b + 2] + f[i].w * sWm2[b + 3];
        klv_p += f[i].x * sWl2[b] + f[i].y * sWl2[b + 1] + f[i].z * sWl2[b + 2] + f[i].w * sWl2[b + 3];
      }
      #pragma unroll
      for (int i = 0; i < 4; ++i) {
        float4 a = f[2 * i], b2 = f[2 * i + 1];
        bf16x8 v = {(bf16_t)a.x,  (bf16_t)a.y,  (bf16_t)a.z,  (bf16_t)a.w,
                    (bf16_t)b2.x, (bf16_t)b2.y, (bf16_t)b2.z, (bf16_t)b2.w};
        *(bf16x8*)(&sK[swz(key, d0 + i * 8)]) = v;
      }
      kmu_p += __shfl_xor(kmu_p, 1); kmu_p += __shfl_xor(kmu_p, 2);
      klv_p += __shfl_xor(klv_p, 1); klv_p += __shfl_xor(klv_p, 2);
      if ((t & 3) == 0) { sKmu[gkey] = kmu_p; sKlv[gkey] = klv_p; }
    }
    __syncthreads();

    // ---- MFMA: wave handles keys [wave*16, wave*16+16); h = relu(K W1^T + b1); mup = h . W2
    f32x4 acc[8];
    #pragma unroll
    for (int et = 0; et < 8; ++et) acc[et] = 0;

    const int arow = wave * 16 + rr;
    #pragma unroll
    for (int kt = 0; kt < 4; ++kt) {
      int dlo = kt * 32 + rg * 4;
      bf16x4 alo = *(const bf16x4*)(&sK[swz(arow, dlo)]);
      bf16x4 ahi = *(const bf16x4*)(&sK[swz(arow, dlo + 16)]);
      bf16x8 a = {alo[0], alo[1], alo[2], alo[3], ahi[0], ahi[1], ahi[2], ahi[3]};
      #pragma unroll
      for (int et = 0; et < 8; ++et) {
        int erow = et * 16 + rr;
        bf16x4 blo = *(const bf16x4*)(&sW[swz(erow, dlo)]);
        bf16x4 bhi = *(const bf16x4*)(&sW[swz(erow, dlo + 16)]);
        bf16x8 b = {blo[0], blo[1], blo[2], blo[3], bhi[0], bhi[1], bhi[2], bhi[3]};
        acc[et] = __builtin_amdgcn_mfma_f32_16x16x32_bf16(a, b, acc[et], 0, 0, 0);
      }
    }
    // epilogue: relu + dot with W2, reduce over the 16 e-cols held across lanes
    float mup[4] = {0.f, 0.f, 0.f, 0.f};
    #pragma unroll
    for (int et = 0; et < 8; ++et) {
      int e = et * 16 + rr;
      float b1 = sB1[e], w2 = sW2[e];
      #pragma unroll
      for (int r = 0; r < 4; ++r) {
        float h = fmaxf(acc[et][r] + b1, 0.f);
        mup[r] += h * w2;
      }
    }
    #pragma unroll
    for (int r = 0; r < 4; ++r) {
      mup[r] += __shfl_xor(mup[r], 1);
      mup[r] += __shfl_xor(mup[r], 2);
      mup[r] += __shfl_xor(mup[r], 4);
      mup[r] += __shfl_xor(mup[r], 8);
    }
    if (rr == 0) {
      #pragma unroll
      for (int r = 0; r < 4; ++r)
        sMup[chunk * 64 + wave * 16 + rg * 4 + r] = mup[r] + b_p2 - 0.5f;
    }
    __syncthreads();   // sMup done; sK free for next chunk
  }

  // ================= posterior, KL, samples =================
  float klacc = 0.f, smax = -1e30f;
  float sval[2];
  #pragma unroll
  for (int i = 0; i < 2; ++i) {
    int k = t + i * 256;
    float kmu = sKmu[k], klv = sKlv[k], mupr = sMup[k];
    float mu0 = qmu + kmu + b_mu;
    float lv  = qlv + klv + b_lv;
    float sp  = expf(0.5f * lv);
    float sp2 = sp * sp;
    float mu  = mu0 - 0.5f * sp2;
    float dd  = mu - mupr;
    klacc += -0.5f * lv + 0.5f * (sp2 + dd * dd) - 0.5f;
    float s = expf(mu + sp * eps[(size_t)q * NK + k]);
    sval[i] = s;
    sS[k] = s;
    smax = fmaxf(smax, s);
  }
  float mx = blockMax(smax, sRed);
  float esum = 0.f, ev[2];
  #pragma unroll
  for (int i = 0; i < 2; ++i) { ev[i] = expf(sval[i] - mx); esum += ev[i]; }
  float tot = blockSum(esum, sRed);
  float inv = 1.f / tot;
  #pragma unroll
  for (int i = 0; i < 2; ++i) sS[t + i * 256] = ev[i] * inv;   // weights
  float klb = blockSum(klacc, sRed);   // also orders sS writes before phase 3
  if (t == 0) klp[q] = klb;

  // ================= context = weights . V, then LayerNorm =================
  float* sCtx = reinterpret_cast<float*>(sK);   // 8 x 128 f32 (sK dead)
  {
    int slot = t >> 5, l16 = t & 31;
    f32x4 acc = 0;
    const float4* V4 = reinterpret_cast<const float4*>(V + (size_t)q * NK * 128);
    for (int key = slot; key < NK; key += 8) {
      float w = sS[key];
      float4 v = V4[key * 32 + l16];
      acc.x += w * v.x; acc.y += w * v.y; acc.z += w * v.z; acc.w += w * v.w;
    }
    *(f32x4*)(&sCtx[slot * 128 + l16 * 4]) = acc;
  }
  __syncthreads();

  float ctx = 0.f, s1 = 0.f, s2 = 0.f;
  if (t < 128) {
    #pragma unroll
    for (int s = 0; s < 8; ++s) ctx += sCtx[s * 128 + t];
    s1 = ctx; s2 = ctx * ctx;
  }
  float mean = blockSum(s1, sRed) * (1.f / 128.f);
  float msq  = blockSum(s2, sRed) * (1.f / 128.f);
  if (t < 128) {
    float var = fmaxf(msq - mean * mean, 0.f);
    float r = rsqrtf(var + 1e-5f);
    out[(size_t)q * 128 + t] = (ctx - mean) * r * gamma[t] + beta[t];
  }
}

__global__ __launch_bounds__(256) void kl_finalize(const float* __restrict__ part,
                                                   float* __restrict__ out) {
  __shared__ float sRed[4];
  float v = 0.f;
  for (int i = threadIdx.x; i < NQ; i += 256) v += part[i];
  #pragma unroll
  for (int m = 32; m; m >>= 1) v += __shfl_xor(v, m);
  if ((threadIdx.x & 63) == 0) sRed[threadIdx.x >> 6] = v;
  __syncthreads();
  if (threadIdx.x == 0)
    out[(size_t)NQ * DD] = (sRed[0] + sRed[1] + sRed[2] + sRed[3]) * (1.f / ((float)NQ * (float)NK));
}

extern "C" void kernel_launch(void* const* d_in, const int* in_sizes, int n_in,
                              void* d_out, int out_size, void* d_ws, size_t ws_size,
                              hipStream_t stream) {
  const float* Q    = (const float*)d_in[0];
  const float* K    = (const float*)d_in[1];
  const float* V    = (const float*)d_in[2];
  const float* eps  = (const float*)d_in[3];
  const float* Wmu  = (const float*)d_in[4];
  const float* bmu  = (const float*)d_in[5];
  const float* Wlv  = (const float*)d_in[6];
  const float* blv  = (const float*)d_in[7];
  const float* Wp1  = (const float*)d_in[8];
  const float* bp1  = (const float*)d_in[9];
  const float* Wp2  = (const float*)d_in[10];
  const float* bp2  = (const float*)d_in[11];
  const float* gam  = (const float*)d_in[12];
  const float* bet  = (const float*)d_in[13];
  float* out = (float*)d_out;
  float* ws  = (float*)d_ws;   // 2048 f32 partial KLs

  fused_np_attn<<<NQ, 256, 0, stream>>>(Q, K, V, eps, Wmu, bmu, Wlv, blv,
                                        Wp1, bp1, Wp2, bp2, gam, bet, out, ws);
  kl_finalize<<<1, 256, 0, stream>>>(ws, out);
}